// Round 1
// baseline (187.407 us; speedup 1.0000x reference)
//
#include <hip/hip_runtime.h>
#include <math.h>

#define NFREQ 17

// ws layout (doubles):
//   ws[0] = sum(x), ws[1] = sum(x^2)
//   ws[2 + p]          = sum(cos(t_{p+1} * xs))   p = 0..16
//   ws[2 + NFREQ + p]  = sum(sin(t_{p+1} * xs))   p = 0..16
// total 36 doubles = 288 bytes

__global__ void init_ws_kernel(double* ws) {
    int i = threadIdx.x;
    if (i < 2 + 2 * NFREQ) ws[i] = 0.0;
}

__global__ void __launch_bounds__(256) stat_kernel(const float* __restrict__ x, long long n,
                                                   double* __restrict__ ws) {
    long long tid = blockIdx.x * (long long)blockDim.x + threadIdx.x;
    long long stride = (long long)gridDim.x * blockDim.x;
    long long n4 = n >> 2;
    const float4* x4 = (const float4*)x;

    double s = 0.0, s2 = 0.0;
    for (long long i = tid; i < n4; i += stride) {
        float4 v = x4[i];
        double a = v.x, b = v.y, c = v.z, d = v.w;
        s += (a + b) + (c + d);
        s2 += (a * a + b * b) + (c * c + d * d);
    }
    // tail (n not divisible by 4) — handled by global thread 0
    if (tid == 0) {
        for (long long i = n4 << 2; i < n; ++i) {
            double a = x[i];
            s += a;
            s2 += a * a;
        }
    }

    // wave (64-lane) reduce in fp64
    for (int off = 32; off > 0; off >>= 1) {
        s  += __shfl_down(s, off);
        s2 += __shfl_down(s2, off);
    }
    __shared__ double ls[4], ls2[4];
    int lane = threadIdx.x & 63;
    int wid  = threadIdx.x >> 6;
    if (lane == 0) { ls[wid] = s; ls2[wid] = s2; }
    __syncthreads();
    if (threadIdx.x == 0) {
        double S = ls[0] + ls[1] + ls[2] + ls[3];
        double S2 = ls2[0] + ls2[1] + ls2[2] + ls2[3];
        atomicAdd(&ws[0], S);
        atomicAdd(&ws[1], S2);
    }
}

__global__ void __launch_bounds__(256) ecf_kernel(const float* __restrict__ x, long long n,
                                                  double* __restrict__ ws) {
    // mu / sd from the fp64 sums (every thread — 2 loads + a few fp64 ops, trivial)
    double mu_d = ws[0] / (double)n;
    double var = (ws[1] - (double)n * mu_d * mu_d) / (double)(n - 1);
    double sd = sqrt(var);
    float inv_sd = (float)(1.0 / (sd + 1e-8));
    float muf = (float)mu_d;
    const float dt = (float)(2.0 / 17.0);
    float scale = inv_sd * dt;  // base angle per element = (x - mu) * scale; arg_p = (p+1)*base

    float ac[NFREQ], as_[NFREQ];
#pragma unroll
    for (int p = 0; p < NFREQ; ++p) { ac[p] = 0.0f; as_[p] = 0.0f; }

    long long tid = blockIdx.x * (long long)blockDim.x + threadIdx.x;
    long long stride = (long long)gridDim.x * blockDim.x;
    long long n4 = n >> 2;
    const float4* x4 = (const float4*)x;

    for (long long i = tid; i < n4; i += stride) {
        float4 v = x4[i];
        float e[4] = {v.x, v.y, v.z, v.w};
#pragma unroll
        for (int j = 0; j < 4; ++j) {
            float base = (e[j] - muf) * scale;
#pragma unroll
            for (int p = 0; p < NFREQ; ++p) {
                float sv, cv;
                sincosf(base * (float)(p + 1), &sv, &cv);
                ac[p] += cv;
                as_[p] += sv;
            }
        }
    }
    // tail — global thread 0
    if (tid == 0) {
        for (long long i = n4 << 2; i < n; ++i) {
            float base = (x[i] - muf) * scale;
#pragma unroll
            for (int p = 0; p < NFREQ; ++p) {
                float sv, cv;
                sincosf(base * (float)(p + 1), &sv, &cv);
                ac[p] += cv;
                as_[p] += sv;
            }
        }
    }

    // fp32 wave reduce (per-accumulator magnitude <= 64*elems_per_thread; rounding noise
    // averages out across 4096 waves — contributes <1e-9 to the mean)
#pragma unroll
    for (int p = 0; p < NFREQ; ++p) {
        for (int off = 32; off > 0; off >>= 1) {
            ac[p]  += __shfl_down(ac[p], off);
            as_[p] += __shfl_down(as_[p], off);
        }
    }
    __shared__ float lc[4][NFREQ];
    __shared__ float lsn[4][NFREQ];
    int lane = threadIdx.x & 63;
    int wid  = threadIdx.x >> 6;
    if (lane == 0) {
#pragma unroll
        for (int p = 0; p < NFREQ; ++p) { lc[wid][p] = ac[p]; lsn[wid][p] = as_[p]; }
    }
    __syncthreads();
    if (threadIdx.x < NFREQ) {
        int p = threadIdx.x;
        double C = (double)lc[0][p] + (double)lc[1][p] + (double)lc[2][p] + (double)lc[3][p];
        double S = (double)lsn[0][p] + (double)lsn[1][p] + (double)lsn[2][p] + (double)lsn[3][p];
        atomicAdd(&ws[2 + p], C);
        atomicAdd(&ws[2 + NFREQ + p], S);
    }
}

__global__ void finalize_kernel(const double* __restrict__ ws, float* __restrict__ out, long long n) {
    if (threadIdx.x == 0 && blockIdx.x == 0) {
        double nd = (double)n;
        double dt = 2.0 / 17.0;
        double total = 0.0;
        for (int p = 1; p <= NFREQ; ++p) {
            double t = 2.0 * (double)p / 17.0;
            double r = ws[2 + (p - 1)] / nd;
            double im = ws[2 + NFREQ + (p - 1)] / nd;
            double tcf = exp(-0.5 * t * t);
            double integrand = r * r + im * im - 2.0 * r * tcf + tcf * tcf;
            double w = (p == 1 || p == NFREQ) ? dt * 0.5 : dt;
            total += w * integrand;
        }
        out[0] = (float)total;
    }
}

extern "C" void kernel_launch(void* const* d_in, const int* in_sizes, int n_in,
                              void* d_out, int out_size, void* d_ws, size_t ws_size,
                              hipStream_t stream) {
    const float* x = (const float*)d_in[0];
    long long n = (long long)in_sizes[0];
    double* ws = (double*)d_ws;
    float* out = (float*)d_out;

    init_ws_kernel<<<1, 64, 0, stream>>>(ws);
    stat_kernel<<<2048, 256, 0, stream>>>(x, n, ws);
    ecf_kernel<<<1024, 256, 0, stream>>>(x, n, ws);
    finalize_kernel<<<1, 64, 0, stream>>>(ws, out, n);
}

// Round 2
// 65.527 us; speedup vs baseline: 2.8600x; 2.8600x over previous
//
#include <hip/hip_runtime.h>
#include <math.h>

#define NFREQ 17
#define STAT_BLOCKS 512
#define ECF_BLOCKS 1024

// ws layout (doubles):
//   [0 .. 2*STAT_BLOCKS)                  stat partials: block b -> {sum, sumsq}
//   [SPAD .. SPAD + ECF_BLOCKS*34)        ecf partials: block b -> 17 cos sums, 17 sin sums (fp64)
#define SPAD (2 * STAT_BLOCKS)

__global__ void __launch_bounds__(256) stat_kernel(const float* __restrict__ x, long long n,
                                                   double* __restrict__ ws) {
    long long tid = blockIdx.x * (long long)blockDim.x + threadIdx.x;
    long long stride = (long long)gridDim.x * blockDim.x;
    long long n4 = n >> 2;
    const float4* x4 = (const float4*)x;

    double s = 0.0, s2 = 0.0;
    for (long long i = tid; i < n4; i += stride) {
        float4 v = x4[i];
        double a = v.x, b = v.y, c = v.z, d = v.w;
        s += (a + b) + (c + d);
        s2 += (a * a + b * b) + (c * c + d * d);
    }
    if (tid == 0) {  // tail
        for (long long i = n4 << 2; i < n; ++i) {
            double a = x[i];
            s += a;
            s2 += a * a;
        }
    }

    for (int off = 32; off > 0; off >>= 1) {
        s  += __shfl_down(s, off);
        s2 += __shfl_down(s2, off);
    }
    __shared__ double ls[4], ls2[4];
    int lane = threadIdx.x & 63;
    int wid  = threadIdx.x >> 6;
    if (lane == 0) { ls[wid] = s; ls2[wid] = s2; }
    __syncthreads();
    if (threadIdx.x == 0) {
        ws[2 * blockIdx.x + 0] = ls[0] + ls[1] + ls[2] + ls[3];
        ws[2 * blockIdx.x + 1] = ls2[0] + ls2[1] + ls2[2] + ls2[3];
    }
}

__global__ void __launch_bounds__(256) ecf_kernel(const float* __restrict__ x, long long n,
                                                  double* __restrict__ ws) {
    // ---- prologue: every block reduces the STAT_BLOCKS partials to mu/scale ----
    __shared__ double rls[4], rls2[4];
    __shared__ float sh_mu, sh_scale;
    {
        double s = 0.0, s2 = 0.0;
        for (int i = threadIdx.x; i < STAT_BLOCKS; i += 256) {
            s  += ws[2 * i + 0];
            s2 += ws[2 * i + 1];
        }
        for (int off = 32; off > 0; off >>= 1) {
            s  += __shfl_down(s, off);
            s2 += __shfl_down(s2, off);
        }
        int lane = threadIdx.x & 63;
        int wid  = threadIdx.x >> 6;
        if (lane == 0) { rls[wid] = s; rls2[wid] = s2; }
        __syncthreads();
        if (threadIdx.x == 0) {
            double S  = rls[0] + rls[1] + rls[2] + rls[3];
            double S2 = rls2[0] + rls2[1] + rls2[2] + rls2[3];
            double mu_d = S / (double)n;
            double var = (S2 - (double)n * mu_d * mu_d) / (double)(n - 1);
            double sd = sqrt(var);
            sh_mu = (float)mu_d;
            sh_scale = (float)((2.0 / 17.0) / (sd + 1e-8));
        }
        __syncthreads();
    }
    const float muf = sh_mu;
    const float scale = sh_scale;

    float ac[NFREQ], as_[NFREQ];
#pragma unroll
    for (int p = 0; p < NFREQ; ++p) { ac[p] = 0.0f; as_[p] = 0.0f; }

    long long tid = blockIdx.x * (long long)blockDim.x + threadIdx.x;
    long long stride = (long long)gridDim.x * blockDim.x;
    long long n4 = n >> 2;
    const float4* x4 = (const float4*)x;

    for (long long i = tid; i < n4; i += stride) {
        float4 v = x4[i];
        float e[4] = {v.x, v.y, v.z, v.w};
#pragma unroll
        for (int j = 0; j < 4; ++j) {
            float th = (e[j] - muf) * scale;
            float s1, c1;
            sincosf(th, &s1, &c1);
            float k2 = c1 + c1;
            // Chebyshev 3-term: f_p = 2*c1*f_{p-1} - f_{p-2}
            float cm2 = 1.0f, cm1 = c1;
            float sm2 = 0.0f, sm1 = s1;
            ac[0] += c1; as_[0] += s1;
#pragma unroll
            for (int p = 1; p < NFREQ; ++p) {
                float cp = __builtin_fmaf(k2, cm1, -cm2);
                float sp = __builtin_fmaf(k2, sm1, -sm2);
                ac[p] += cp; as_[p] += sp;
                cm2 = cm1; cm1 = cp;
                sm2 = sm1; sm1 = sp;
            }
        }
    }
    if (tid == 0) {  // tail
        for (long long i = n4 << 2; i < n; ++i) {
            float th = (x[i] - muf) * scale;
            float s1, c1;
            sincosf(th, &s1, &c1);
            float k2 = c1 + c1;
            float cm2 = 1.0f, cm1 = c1;
            float sm2 = 0.0f, sm1 = s1;
            ac[0] += c1; as_[0] += s1;
#pragma unroll
            for (int p = 1; p < NFREQ; ++p) {
                float cp = __builtin_fmaf(k2, cm1, -cm2);
                float sp = __builtin_fmaf(k2, sm1, -sm2);
                ac[p] += cp; as_[p] += sp;
                cm2 = cm1; cm1 = cp;
                sm2 = sm1; sm1 = sp;
            }
        }
    }

    // fp32 wave reduce, then fp64 across the 4 waves (same structure as R1)
#pragma unroll
    for (int p = 0; p < NFREQ; ++p) {
        for (int off = 32; off > 0; off >>= 1) {
            ac[p]  += __shfl_down(ac[p], off);
            as_[p] += __shfl_down(as_[p], off);
        }
    }
    __shared__ float lc[4][NFREQ];
    __shared__ float lsn[4][NFREQ];
    int lane = threadIdx.x & 63;
    int wid  = threadIdx.x >> 6;
    if (lane == 0) {
#pragma unroll
        for (int p = 0; p < NFREQ; ++p) { lc[wid][p] = ac[p]; lsn[wid][p] = as_[p]; }
    }
    __syncthreads();
    if (threadIdx.x < 2 * NFREQ) {
        int j = threadIdx.x;
        double v;
        if (j < NFREQ) {
            v = (double)lc[0][j] + (double)lc[1][j] + (double)lc[2][j] + (double)lc[3][j];
        } else {
            int p = j - NFREQ;
            v = (double)lsn[0][p] + (double)lsn[1][p] + (double)lsn[2][p] + (double)lsn[3][p];
        }
        ws[SPAD + (long long)blockIdx.x * (2 * NFREQ) + j] = v;
    }
}

__global__ void __launch_bounds__(256) finalize_kernel(const double* __restrict__ ws,
                                                       float* __restrict__ out, long long n) {
    __shared__ double sums[2 * NFREQ];
    int tid = threadIdx.x;
    if (tid < 2 * NFREQ) {
        const double* P = ws + SPAD;
        double a0 = 0.0, a1 = 0.0, a2 = 0.0, a3 = 0.0;
        for (int b = 0; b < ECF_BLOCKS; b += 4) {
            a0 += P[(long long)(b + 0) * (2 * NFREQ) + tid];
            a1 += P[(long long)(b + 1) * (2 * NFREQ) + tid];
            a2 += P[(long long)(b + 2) * (2 * NFREQ) + tid];
            a3 += P[(long long)(b + 3) * (2 * NFREQ) + tid];
        }
        sums[tid] = (a0 + a1) + (a2 + a3);
    }
    __syncthreads();
    if (tid == 0) {
        double nd = (double)n;
        double dt = 2.0 / 17.0;
        double total = 0.0;
        for (int k = 1; k <= NFREQ; ++k) {
            double t = 2.0 * (double)k / 17.0;
            double r  = sums[k - 1] / nd;
            double im = sums[NFREQ + k - 1] / nd;
            double tcf = exp(-0.5 * t * t);
            double integrand = r * r + im * im - 2.0 * r * tcf + tcf * tcf;
            double w = (k == 1 || k == NFREQ) ? dt * 0.5 : dt;
            total += w * integrand;
        }
        out[0] = (float)total;
    }
}

extern "C" void kernel_launch(void* const* d_in, const int* in_sizes, int n_in,
                              void* d_out, int out_size, void* d_ws, size_t ws_size,
                              hipStream_t stream) {
    const float* x = (const float*)d_in[0];
    long long n = (long long)in_sizes[0];
    double* ws = (double*)d_ws;
    float* out = (float*)d_out;

    stat_kernel<<<STAT_BLOCKS, 256, 0, stream>>>(x, n, ws);
    ecf_kernel<<<ECF_BLOCKS, 256, 0, stream>>>(x, n, ws);
    finalize_kernel<<<1, 256, 0, stream>>>(ws, out, n);
}